// Round 1
// baseline (419.493 us; speedup 1.0000x reference)
//
#include <hip/hip_runtime.h>
#include <hip/hip_bf16.h>
#include <stdint.h>

#define BN 16
#define SN 2048
#define DN 128
#define SCALE 0.08838834764831845f   // 1/sqrt(128)

typedef float  f32x4  __attribute__((ext_vector_type(4)));
typedef short  s16x8  __attribute__((ext_vector_type(8)));
typedef short  s16x4  __attribute__((ext_vector_type(4)));
typedef __bf16 bf16x8 __attribute__((ext_vector_type(8)));

static __device__ __forceinline__ bf16x8 as_bf(s16x8 v) {
    return __builtin_bit_cast(bf16x8, v);
}
static __device__ __forceinline__ short f2bf(float f) {
    return __builtin_bit_cast(short, (__bf16)f);
}

// ---------------------------------------------------------------- prep: cast
__global__ void cast_bf16_kernel(const float* __restrict__ src,
                                 short* __restrict__ dst, int n4) {
    int idx = blockIdx.x * blockDim.x + threadIdx.x;
    if (idx >= n4) return;
    const float4 v = ((const float4*)src)[idx];
    s16x4 o;
    o[0] = f2bf(v.x); o[1] = f2bf(v.y); o[2] = f2bf(v.z); o[3] = f2bf(v.w);
    ((s16x4*)dst)[idx] = o;
}

// ------------------------------------------------- prep: V -> V^T (bf16)
// Vt[b][d][s] so PV B-fragments are contiguous along the k (=j) axis.
__global__ void transpose_v_kernel(const float* __restrict__ V,
                                   short* __restrict__ Vt) {
    __shared__ float tile[64][65];
    const int b = blockIdx.z, j0 = blockIdx.x * 64, d0 = blockIdx.y * 64;
    const int t = threadIdx.x;
    const int r = t >> 4, c4 = (t & 15) * 4;
    const float* src = V + ((size_t)b * SN + j0) * DN + d0;
    for (int it = 0; it < 4; ++it) {
        int rr = r + it * 16;
        const float4 v = *(const float4*)(src + (size_t)rr * DN + c4);
        tile[rr][c4 + 0] = v.x; tile[rr][c4 + 1] = v.y;
        tile[rr][c4 + 2] = v.z; tile[rr][c4 + 3] = v.w;
    }
    __syncthreads();
    short* dst = Vt + ((size_t)b * DN + d0) * SN + j0;
    for (int it = 0; it < 4; ++it) {
        int dr = r + it * 16;   // local d row
        s16x4 o;
        o[0] = f2bf(tile[c4 + 0][dr]);
        o[1] = f2bf(tile[c4 + 1][dr]);
        o[2] = f2bf(tile[c4 + 2][dr]);
        o[3] = f2bf(tile[c4 + 3][dr]);
        *(s16x4*)(dst + (size_t)dr * SN + c4) = o;
    }
}

// ------------------------------------- zero the far upper triangle of W
// main kernel covers cols [0, (qt+1)*64) for row-tile qt; we cover the rest.
__global__ void zero_upper_kernel(float* __restrict__ W) {
    const int c0 = blockIdx.x * 128;
    const int qt = blockIdx.y;
    const int b  = blockIdx.z;
    const int z0 = (qt + 1) * 64;
    if (c0 + 128 <= z0) return;
    float* base = W + ((size_t)b * SN + qt * 64) * SN;
    const int t = threadIdx.x;
    const f32x4 z = {0.f, 0.f, 0.f, 0.f};
    for (int k = 0; k < 8; ++k) {
        int idx = t + k * 256;          // 0..2047 -> 64 rows x 32 float4
        int r = idx >> 5;
        int c = c0 + ((idx & 31) << 2);
        if (c >= z0) *(f32x4*)(base + (size_t)r * SN + c) = z;
    }
}

// ------------------------------------------------------------- attention
// Block: 256 threads = 4 waves; TQ=64 rows (16/wave), K-tiles of 64.
// Pass 1: exact row max & sum-exp (MFMA scores, quad shuffles).
// Pass 2: recompute scores, write normalized W (fp32), P->LDS, PV MFMA.
__launch_bounds__(256, 2)
__global__ void attn_kernel(const short* __restrict__ Qb,
                            const short* __restrict__ Kb,
                            const short* __restrict__ Vtb,
                            float* __restrict__ O,
                            float* __restrict__ W) {
    __shared__ short Ks[64 * 136];   // K tile, row-major [j][d], pad 8
    __shared__ short Vs[128 * 72];   // V^T tile, [d][j], pad 8
    __shared__ short Ps[64 * 72];    // P tile, row-major [i][j], pad 8

    const int tid  = threadIdx.x;
    const int wave = tid >> 6;
    const int lane = tid & 63;
    const int l15  = lane & 15;
    const int quad = lane >> 4;

    // pair block n with n+256 so per-CU causal work is ~constant
    const int idx  = blockIdx.x;
    const int half = idx >> 8;
    const int rr_  = idx & 255;
    const int b    = ((rr_ >> 5) << 1) | half;
    const int qr   = rr_ & 31;
    const int qt   = half ? (31 - qr) : qr;
    const int i0   = qt * 64;
    const int ntiles = qt + 1;

    // Q fragments: A[m=l15][k=quad*8+j], 4 k-steps of 32
    bf16x8 qf[4];
    {
        const short* qp = Qb + ((size_t)b * SN + (i0 + wave * 16 + l15)) * DN + quad * 8;
        for (int ks = 0; ks < 4; ++ks)
            qf[ks] = as_bf(*(const s16x8*)(qp + ks * 32));
    }

    float m_[4], l_[4];
    for (int g = 0; g < 4; ++g) { m_[g] = -1e30f; l_[g] = 0.f; }

    const short* kbase = Kb  + (size_t)b * SN * DN;
    const short* vbase = Vtb + (size_t)b * DN * SN;

    // ---------------- pass 1: m, l ----------------
    for (int tI = 0; tI < ntiles; ++tI) {
        const int j0 = tI * 64;
        __syncthreads();
        {   // stage K tile (bf16, coalesced dwordx4 -> ds_write_b128)
            const int row = tid >> 4, d0 = (tid & 15) * 8;
            for (int it = 0; it < 4; ++it) {
                int rj = row + it * 16;
                *(s16x8*)(Ks + rj * 136 + d0) =
                    *(const s16x8*)(kbase + (size_t)(j0 + rj) * DN + d0);
            }
        }
        __syncthreads();

        f32x4 sacc[4];
        for (int ct = 0; ct < 4; ++ct) {
            f32x4 c = {0.f, 0.f, 0.f, 0.f};
            const short* kp = Ks + (ct * 16 + l15) * 136 + quad * 8;
            for (int ks = 0; ks < 4; ++ks)
                c = __builtin_amdgcn_mfma_f32_16x16x32_bf16(
                        qf[ks], as_bf(*(const s16x8*)(kp + ks * 32)), c, 0, 0, 0);
            sacc[ct] = c * SCALE;
        }
        if (j0 == i0) {  // straddle tile: mask j > i
            for (int ct = 0; ct < 4; ++ct)
                for (int g = 0; g < 4; ++g) {
                    int i = i0 + wave * 16 + quad * 4 + g;
                    int j = j0 + ct * 16 + l15;
                    if (j > i) sacc[ct][g] = -1e30f;
                }
        }
        for (int g = 0; g < 4; ++g) {
            float tm = fmaxf(fmaxf(sacc[0][g], sacc[1][g]),
                             fmaxf(sacc[2][g], sacc[3][g]));
            for (int msk = 1; msk < 16; msk <<= 1)
                tm = fmaxf(tm, __shfl_xor(tm, msk));
            float mn = fmaxf(m_[g], tm);
            float ps = 0.f;
            for (int ct = 0; ct < 4; ++ct) ps += __expf(sacc[ct][g] - mn);
            for (int msk = 1; msk < 16; msk <<= 1)
                ps += __shfl_xor(ps, msk);
            l_[g] = l_[g] * __expf(m_[g] - mn) + ps;
            m_[g] = mn;
        }
    }

    float rl[4];
    for (int g = 0; g < 4; ++g) rl[g] = 1.f / l_[g];

    f32x4 oacc[8];
    const f32x4 zero4 = {0.f, 0.f, 0.f, 0.f};
    for (int nt = 0; nt < 8; ++nt) oacc[nt] = zero4;

    float* wrow = W + ((size_t)b * SN + i0 + wave * 16 + quad * 4) * SN + l15;

    // ---------------- pass 2: W writes + PV ----------------
    for (int tI = 0; tI < ntiles; ++tI) {
        const int j0 = tI * 64;
        __syncthreads();
        {   // stage K tile + V^T tile
            const int row = tid >> 4, d0 = (tid & 15) * 8;
            for (int it = 0; it < 4; ++it) {
                int rj = row + it * 16;
                *(s16x8*)(Ks + rj * 136 + d0) =
                    *(const s16x8*)(kbase + (size_t)(j0 + rj) * DN + d0);
            }
            const int dd = tid >> 3, jj0 = (tid & 7) * 8;
            for (int it = 0; it < 4; ++it) {
                int dr = dd + it * 32;
                *(s16x8*)(Vs + dr * 72 + jj0) =
                    *(const s16x8*)(vbase + (size_t)dr * SN + j0 + jj0);
            }
        }
        __syncthreads();

        f32x4 sacc[4];
        for (int ct = 0; ct < 4; ++ct) {
            f32x4 c = {0.f, 0.f, 0.f, 0.f};
            const short* kp = Ks + (ct * 16 + l15) * 136 + quad * 8;
            for (int ks = 0; ks < 4; ++ks)
                c = __builtin_amdgcn_mfma_f32_16x16x32_bf16(
                        qf[ks], as_bf(*(const s16x8*)(kp + ks * 32)), c, 0, 0, 0);
            sacc[ct] = c * SCALE;
        }
        if (j0 == i0) {
            for (int ct = 0; ct < 4; ++ct)
                for (int g = 0; g < 4; ++g) {
                    int i = i0 + wave * 16 + quad * 4 + g;
                    int j = j0 + ct * 16 + l15;
                    if (j > i) sacc[ct][g] = -1e30f;
                }
        }
        // normalized weights: fp32 to global, bf16 to LDS (P)
        for (int ct = 0; ct < 4; ++ct) {
            for (int g = 0; g < 4; ++g) {
                float wv = __expf(sacc[ct][g] - m_[g]) * rl[g];  // masked -> 0
                wrow[(size_t)g * SN + j0 + ct * 16] = wv;
                Ps[(wave * 16 + quad * 4 + g) * 72 + ct * 16 + l15] = f2bf(wv);
            }
        }
        // PV: O += P·V  (A from Ps, B from Vs; same-wave LDS, HW in-order)
        bf16x8 pf[2];
        const short* pp = Ps + (wave * 16 + l15) * 72 + quad * 8;
        pf[0] = as_bf(*(const s16x8*)(pp));
        pf[1] = as_bf(*(const s16x8*)(pp + 32));
        for (int nt = 0; nt < 8; ++nt) {
            const short* vp = Vs + (nt * 16 + l15) * 72 + quad * 8;
            f32x4 c = oacc[nt];
            c = __builtin_amdgcn_mfma_f32_16x16x32_bf16(
                    pf[0], as_bf(*(const s16x8*)(vp)), c, 0, 0, 0);
            c = __builtin_amdgcn_mfma_f32_16x16x32_bf16(
                    pf[1], as_bf(*(const s16x8*)(vp + 32)), c, 0, 0, 0);
            oacc[nt] = c;
        }
    }

    float* orow = O + ((size_t)b * SN + i0 + wave * 16 + quad * 4) * DN + l15;
    for (int nt = 0; nt < 8; ++nt)
        for (int g = 0; g < 4; ++g)
            orow[(size_t)g * DN + nt * 16] = oacc[nt][g];
}

// ---------------------------------------------------------------- launch
extern "C" void kernel_launch(void* const* d_in, const int* in_sizes, int n_in,
                              void* d_out, int out_size, void* d_ws, size_t ws_size,
                              hipStream_t stream) {
    const float* Q = (const float*)d_in[0];
    const float* K = (const float*)d_in[1];
    const float* V = (const float*)d_in[2];
    float* O = (float*)d_out;
    float* W = O + (size_t)BN * SN * DN;   // weights follow output in d_out

    short* Qb = (short*)d_ws;
    short* Kb = Qb + (size_t)BN * SN * DN;
    short* Vt = Kb + (size_t)BN * SN * DN;

    const int n4 = (BN * SN * DN) / 4;     // 1,048,576 float4 groups
    cast_bf16_kernel<<<n4 / 256, 256, 0, stream>>>(Q, Qb, n4);
    cast_bf16_kernel<<<n4 / 256, 256, 0, stream>>>(K, Kb, n4);
    transpose_v_kernel<<<dim3(SN / 64, DN / 64, BN), 256, 0, stream>>>(V, Vt);
    zero_upper_kernel<<<dim3(16, 32, 16), 256, 0, stream>>>(W);
    attn_kernel<<<512, 256, 0, stream>>>(Qb, Kb, Vt, O, W);
}